// Round 1
// baseline (637.734 us; speedup 1.0000x reference)
//
#include <hip/hip_runtime.h>

#define RAD 5
#define BX 32              // output tile width (pixels)
#define BY 16              // output tile height
#define PX 2               // pixels per thread in x
#define NTX 16             // threads in x (NTX*PX == BX)
#define NTY 16             // threads in y (== BY)
#define TW (BX + 2*RAD)    // 42 halo tile width
#define TH (BY + 2*RAD)    // 26 halo tile height
#define TWP (TW + 1)       // 43 padded LDS row stride

// g[|d|] = exp(-d*d/8)
__device__ __constant__ const float kG[6] = {
    1.0f, 0.88249692f, 0.60653066f, 0.32465247f, 0.13533528f, 0.04393693f};
// invd[|dy|][|dx|] = 1/sqrt(dy^2+dx^2); center sentinel 1e30 -> min() clamps to 1e4
__device__ __constant__ const float kINVD[6][6] = {
    {1e30f,       1.0f,        0.5f,        0.33333333f, 0.25f,       0.2f},
    {1.0f,        0.70710678f, 0.44721360f, 0.31622777f, 0.24253563f, 0.19611614f},
    {0.5f,        0.44721360f, 0.35355339f, 0.27735010f, 0.22360680f, 0.18569534f},
    {0.33333333f, 0.31622777f, 0.27735010f, 0.23570226f, 0.2f,        0.17149859f},
    {0.25f,       0.24253563f, 0.22360680f, 0.2f,        0.17677670f, 0.15617376f},
    {0.2f,        0.19611614f, 0.18569534f, 0.17149859f, 0.15617376f, 0.14142136f}};

__global__ __launch_bounds__(256) void bilateral_kernel(
    const float* __restrict__ col, const float* __restrict__ nrm,
    const float* __restrict__ zdz, float* __restrict__ out,
    int H, int W) {
  __shared__ float4 s_a[TH][TWP];  // col.rgb, z
  __shared__ float4 s_b[TH][TWP];  // nrm.xyz, dz

  const int bx = blockIdx.x, by = blockIdx.y, bz = blockIdx.z;
  const int gx0 = bx * BX - RAD;
  const int gy0 = by * BY - RAD;
  const int tid = threadIdx.x;
  const int plane = bz * H * W;

  // ---- stage halo tile into LDS (OOB -> zeros => weight 0, matches mask) ----
  for (int i = tid; i < TH * TW; i += 256) {
    const int r = i / TW;
    const int c = i - r * TW;
    const int gy = gy0 + r, gx = gx0 + c;
    float4 a = make_float4(0.f, 0.f, 0.f, 0.f);
    float4 b = make_float4(0.f, 0.f, 0.f, 0.f);
    if ((unsigned)gy < (unsigned)H && (unsigned)gx < (unsigned)W) {
      const int pix = plane + gy * W + gx;
      const float* cp = col + pix * 3;
      a.x = cp[0]; a.y = cp[1]; a.z = cp[2];
      const float* np_ = nrm + pix * 3;
      b.x = np_[0]; b.y = np_[1]; b.z = np_[2];
      const float* zp = zdz + pix * 2;
      a.w = zp[0]; b.w = zp[1];
    }
    s_a[r][c] = a;
    s_b[r][c] = b;
  }
  __syncthreads();

  const int tx = tid & (NTX - 1);
  const int ty = tid >> 4;
  const int ly = ty + RAD;
  const int lxbase = tx * PX;  // tap x = lxbase + u ; center p at lxbase+RAD+p

  float cnx[PX], cny[PX], cnz[PX], czv[PX], rc[PX];
  float accx[PX], accy[PX], accz[PX], accw[PX];
#pragma unroll
  for (int p = 0; p < PX; ++p) {
    const float4 a = s_a[ly][lxbase + RAD + p];
    const float4 b = s_b[ly][lxbase + RAD + p];
    cnx[p] = b.x; cny[p] = b.y; cnz[p] = b.z;
    czv[p] = a.w;
    rc[p] = 1.0f / b.w;  // 1/cdz (inf ok: min() clamp below)
    accx[p] = 0.f; accy[p] = 0.f; accz[p] = 0.f; accw[p] = 0.f;
  }

#pragma unroll
  for (int dy = -RAD; dy <= RAD; ++dy) {
    const int ady = dy < 0 ? -dy : dy;
#pragma unroll
    for (int u = 0; u < 2 * RAD + PX; ++u) {  // 12 tap columns serve PX pixels
      const float4 a = s_a[ly + dy][lxbase + u];
      const float4 b = s_b[ly + dy][lxbase + u];
#pragma unroll
      for (int p = 0; p < PX; ++p) {
        const int dx = u - RAD - p;
        if (dx < -RAD || dx > RAD) continue;
        const int adx = dx < 0 ? -dx : dx;
        const float wxy = kG[ady] * kG[adx];       // compile-time constant
        const float invd = kINVD[ady][adx];        // compile-time constant
        float d = fmaf(b.x, cnx[p], fmaf(b.y, cny[p], b.z * cnz[p]));
        float wn = fmaxf(d, 0.0f);
        wn = wn * wn; wn = wn * wn; wn = wn * wn; wn = wn * wn;
        wn = wn * wn; wn = wn * wn; wn = wn * wn;  // ^128
        const float il = fminf(rc[p] * invd, 1e4f);  // 1/max(cdz*dist,1e-4)
        const float wd = __expf(-fabsf(a.w - czv[p]) * il);
        const float w = wxy * wn * wd;
        accx[p] = fmaf(a.x, w, accx[p]);
        accy[p] = fmaf(a.y, w, accy[p]);
        accz[p] = fmaf(a.z, w, accz[p]);
        accw[p] += w;
      }
    }
  }

#pragma unroll
  for (int p = 0; p < PX; ++p) {
    const int ox = bx * BX + tx * PX + p;
    const int oy = by * BY + ty;
    const int pix = plane + oy * W + ox;
    const float inv = 1.0f / accw[p];  // center tap weight==1 => accw>=1
    float* op = out + pix * 3;
    op[0] = accx[p] * inv;
    op[1] = accy[p] * inv;
    op[2] = accz[p] * inv;
  }
}

extern "C" void kernel_launch(void* const* d_in, const int* in_sizes, int n_in,
                              void* d_out, int out_size, void* d_ws, size_t ws_size,
                              hipStream_t stream) {
  const float* col = (const float*)d_in[0];
  const float* nrm = (const float*)d_in[1];
  const float* zdz = (const float*)d_in[2];
  float* out = (float*)d_out;
  const int H = 1024, W = 1024;
  const int B = in_sizes[0] / (3 * H * W);
  dim3 grid(W / BX, H / BY, B);
  bilateral_kernel<<<grid, dim3(256), 0, stream>>>(col, nrm, zdz, out, H, W);
}

// Round 2
// 367.023 us; speedup vs baseline: 1.7376x; 1.7376x over previous
//
#include <hip/hip_runtime.h>

#define RAD 5
#define BX 32              // output tile width (pixels)
#define BY 16              // output tile height
#define PX 2               // pixels per thread in x
#define NTX 16             // threads in x (NTX*PX == BX)
#define TW (BX + 2*RAD)    // 42 halo tile width
#define TH (BY + 2*RAD)    // 26 halo tile height
#define TWP (TW + 1)       // 43 padded LDS row stride

#define LOG2E 1.44269504f

// kLG[|d|] = log2(exp(-d*d/8)) = -d*d/(8*ln2)
__device__ __constant__ const float kLG[6] = {
    0.0f, -0.18033688f, -0.72134752f, -1.62303192f, -2.88539008f, -4.50842200f};
// kINVD[|dy|][|dx|] = 1/sqrt(dy^2+dx^2); center sentinel 1e30 -> min() clamps
__device__ __constant__ const float kINVD[6][6] = {
    {1e30f,       1.0f,        0.5f,        0.33333333f, 0.25f,       0.2f},
    {1.0f,        0.70710678f, 0.44721360f, 0.31622777f, 0.24253563f, 0.19611614f},
    {0.5f,        0.44721360f, 0.35355339f, 0.27735010f, 0.22360680f, 0.18569534f},
    {0.33333333f, 0.31622777f, 0.27735010f, 0.23570226f, 0.2f,        0.17149859f},
    {0.25f,       0.24253563f, 0.22360680f, 0.2f,        0.17677670f, 0.15617376f},
    {0.2f,        0.19611614f, 0.18569534f, 0.17149859f, 0.15617376f, 0.14142136f}};

__global__ __launch_bounds__(256, 4) void bilateral_kernel(
    const float* __restrict__ col, const float* __restrict__ nrm,
    const float* __restrict__ zdz, float* __restrict__ out,
    int H, int W) {
  __shared__ float4 s_a[TH][TWP];  // col.rgb, z
  __shared__ float4 s_b[TH][TWP];  // nrm.xyz, dz

  const int bx = blockIdx.x, by = blockIdx.y, bz = blockIdx.z;
  const int gx0 = bx * BX - RAD;
  const int gy0 = by * BY - RAD;
  const int tid = threadIdx.x;
  const int plane = bz * H * W;

  // ---- stage halo tile into LDS (OOB -> zeros => weight 0, matches mask) ----
  for (int i = tid; i < TH * TW; i += 256) {
    const int r = i / TW;
    const int c = i - r * TW;
    const int gy = gy0 + r, gx = gx0 + c;
    float4 a = make_float4(0.f, 0.f, 0.f, 0.f);
    float4 b = make_float4(0.f, 0.f, 0.f, 0.f);
    if ((unsigned)gy < (unsigned)H && (unsigned)gx < (unsigned)W) {
      const int pix = plane + gy * W + gx;
      const float* cp = col + pix * 3;
      a.x = cp[0]; a.y = cp[1]; a.z = cp[2];
      const float* np_ = nrm + pix * 3;
      b.x = np_[0]; b.y = np_[1]; b.z = np_[2];
      const float* zp = zdz + pix * 2;
      a.w = zp[0]; b.w = zp[1];
    }
    s_a[r][c] = a;
    s_b[r][c] = b;
  }
  __syncthreads();

  const int tx = tid & (NTX - 1);
  const int ty = tid >> 4;
  const int ly = ty + RAD;
  const int lxbase = tx * PX;  // tap x = lxbase + u ; center p at lxbase+RAD+p

  float cnx[PX], cny[PX], cnz[PX], czv[PX], rc2[PX];
  float accx[PX], accy[PX], accz[PX], accw[PX];
#pragma unroll
  for (int p = 0; p < PX; ++p) {
    const float4 a = s_a[ly][lxbase + RAD + p];
    const float4 b = s_b[ly][lxbase + RAD + p];
    cnx[p] = b.x; cny[p] = b.y; cnz[p] = b.z;
    czv[p] = a.w;
    rc2[p] = LOG2E / b.w;  // log2e/cdz (inf ok: min() clamp below)
    accx[p] = 0.f; accy[p] = 0.f; accz[p] = 0.f; accw[p] = 0.f;
  }

#pragma unroll 1
  for (int dy = -RAD; dy <= RAD; ++dy) {
    const int ady = dy < 0 ? -dy : dy;
    const float c_row = kLG[ady];          // wave-uniform (SGPR)
    const float* irow = kINVD[ady];        // wave-uniform row pointer
#pragma unroll
    for (int u = 0; u < 2 * RAD + PX; ++u) {  // 12 tap columns serve PX pixels
      const float4 a = s_a[ly + dy][lxbase + u];
      const float4 b = s_b[ly + dy][lxbase + u];
#pragma unroll
      for (int p = 0; p < PX; ++p) {
        const int dx = u - RAD - p;
        if (dx < -RAD || dx > RAD) continue;
        const int adx = dx < 0 ? -dx : dx;
        float d = fmaf(b.x, cnx[p], fmaf(b.y, cny[p], b.z * cnz[p]));
        float wn = fmaxf(d, 0.0f);
        wn = wn * wn; wn = wn * wn; wn = wn * wn; wn = wn * wn;
        wn = wn * wn; wn = wn * wn; wn = wn * wn;  // ^128
        // il2 = log2e / max(cdz*dist, 1e-4)  (clamp rescaled by log2e)
        const float il2 = fminf(rc2[p] * irow[adx], 14426.950f);
        const float tt = fabsf(a.w - czv[p]) * il2;
        // w_xy * w_d = exp2( kLG[adx] + kLG[ady] - |dz|*il*log2e )
        const float e = (kLG[adx] - tt) + c_row;
        const float w = wn * __builtin_amdgcn_exp2f(e);
        accx[p] = fmaf(a.x, w, accx[p]);
        accy[p] = fmaf(a.y, w, accy[p]);
        accz[p] = fmaf(a.z, w, accz[p]);
        accw[p] += w;
      }
    }
  }

#pragma unroll
  for (int p = 0; p < PX; ++p) {
    const int ox = bx * BX + tx * PX + p;
    const int oy = by * BY + ty;
    const int pix = plane + oy * W + ox;
    const float inv = 1.0f / accw[p];  // center tap weight==1 => accw>=1
    float* op = out + pix * 3;
    op[0] = accx[p] * inv;
    op[1] = accy[p] * inv;
    op[2] = accz[p] * inv;
  }
}

extern "C" void kernel_launch(void* const* d_in, const int* in_sizes, int n_in,
                              void* d_out, int out_size, void* d_ws, size_t ws_size,
                              hipStream_t stream) {
  const float* col = (const float*)d_in[0];
  const float* nrm = (const float*)d_in[1];
  const float* zdz = (const float*)d_in[2];
  float* out = (float*)d_out;
  const int H = 1024, W = 1024;
  const int B = in_sizes[0] / (3 * H * W);
  dim3 grid(W / BX, H / BY, B);
  bilateral_kernel<<<grid, dim3(256), 0, stream>>>(col, nrm, zdz, out, H, W);
}

// Round 3
// 333.092 us; speedup vs baseline: 1.9146x; 1.1019x over previous
//
#include <hip/hip_runtime.h>

#define RAD 5
#define BX 32              // output tile width (pixels)
#define BY 16              // output tile height
#define PX 2               // pixels per thread in x
#define NTX 16             // threads in x (NTX*PX == BX)
#define TW (BX + 2*RAD)    // 42 halo tile width
#define TH (BY + 2*RAD)    // 26 halo tile height
#define TWP (TW + 1)       // 43 padded LDS row stride

#define LOG2E 1.44269504f
#define CLAMP2 14426.950f  // 1e4 * log2(e)

// kLG[|d|] = log2(exp(-d*d/8)) = -d*d/(8*ln2)
__device__ __constant__ const float kLG[6] = {
    0.0f, -0.18033688f, -0.72134752f, -1.62303192f, -2.88539008f, -4.50842200f};
// kINVD[|dy|][|dx|] = 1/sqrt(dy^2+dx^2); center sentinel 1e30 -> min() clamps
__device__ __constant__ const float kINVD[6][6] = {
    {1e30f,       1.0f,        0.5f,        0.33333333f, 0.25f,       0.2f},
    {1.0f,        0.70710678f, 0.44721360f, 0.31622777f, 0.24253563f, 0.19611614f},
    {0.5f,        0.44721360f, 0.35355339f, 0.27735010f, 0.22360680f, 0.18569534f},
    {0.33333333f, 0.31622777f, 0.27735010f, 0.23570226f, 0.2f,        0.17149859f},
    {0.25f,       0.24253563f, 0.22360680f, 0.2f,        0.17677670f, 0.15617376f},
    {0.2f,        0.19611614f, 0.18569534f, 0.17149859f, 0.15617376f, 0.14142136f}};

__global__ __launch_bounds__(256, 4) void bilateral_kernel(
    const float* __restrict__ col, const float* __restrict__ nrm,
    const float* __restrict__ zdz, float* __restrict__ out,
    int H, int W) {
  __shared__ float4 s_a[TH][TWP];  // col.rgb, z
  __shared__ float4 s_b[TH][TWP];  // nrm.xyz, dz

  const int bx = blockIdx.x, by = blockIdx.y, bz = blockIdx.z;
  const int gx0 = bx * BX - RAD;
  const int gy0 = by * BY - RAD;
  const int tid = threadIdx.x;
  const int plane = bz * H * W;

  // ---- stage halo tile into LDS (OOB -> zeros => weight 0, matches mask) ----
  for (int i = tid; i < TH * TW; i += 256) {
    const int r = i / TW;
    const int c = i - r * TW;
    const int gy = gy0 + r, gx = gx0 + c;
    float4 a = make_float4(0.f, 0.f, 0.f, 0.f);
    float4 b = make_float4(0.f, 0.f, 0.f, 0.f);
    if ((unsigned)gy < (unsigned)H && (unsigned)gx < (unsigned)W) {
      const int pix = plane + gy * W + gx;
      const float* cp = col + pix * 3;
      a.x = cp[0]; a.y = cp[1]; a.z = cp[2];
      const float* np_ = nrm + pix * 3;
      b.x = np_[0]; b.y = np_[1]; b.z = np_[2];
      const float* zp = zdz + pix * 2;
      a.w = zp[0]; b.w = zp[1];
    }
    s_a[r][c] = a;
    s_b[r][c] = b;
  }
  __syncthreads();

  const int tx = tid & (NTX - 1);
  const int ty = tid >> 4;
  const int ly = ty + RAD;
  const int lxbase = tx * PX;  // tap x = lxbase + u ; center p at lxbase+RAD+p

  float cnx[PX], cny[PX], cnz[PX], czv[PX], rc2[PX];
  float accx[PX], accy[PX], accz[PX], accw[PX];
#pragma unroll
  for (int p = 0; p < PX; ++p) {
    const float4 a = s_a[ly][lxbase + RAD + p];
    const float4 b = s_b[ly][lxbase + RAD + p];
    cnx[p] = b.x; cny[p] = b.y; cnz[p] = b.z;
    czv[p] = a.w;
    rc2[p] = LOG2E / b.w;  // log2e/cdz (inf ok: min() clamp below)
    accx[p] = 0.f; accy[p] = 0.f; accz[p] = 0.f; accw[p] = 0.f;
  }

#pragma unroll 1
  for (int dy = -RAD; dy <= RAD; ++dy) {
    const int ady = dy < 0 ? -dy : dy;
    const float kg_ady = kLG[ady];
    const float* irow = kINVD[ady];
    // per-row hoisted constants: exponent base and clamped inverse-length
    float sA[6];      // kLG[adx] + kLG[ady]
    float il2r[6][PX];  // min(rc2 * invd, clamp)
#pragma unroll
    for (int j = 0; j < 6; ++j) {
      sA[j] = kLG[j] + kg_ady;
      const float iv = irow[j];
#pragma unroll
      for (int p = 0; p < PX; ++p) il2r[j][p] = fminf(rc2[p] * iv, CLAMP2);
    }
#pragma unroll
    for (int u = 0; u < 2 * RAD + PX; ++u) {  // 12 tap columns serve PX pixels
      const float4 a = s_a[ly + dy][lxbase + u];
      const float4 b = s_b[ly + dy][lxbase + u];
#pragma unroll
      for (int p = 0; p < PX; ++p) {
        const int dx = u - RAD - p;
        if (dx < -RAD || dx > RAD) continue;
        const int adx = dx < 0 ? -dx : dx;
        const float d = fmaf(b.x, cnx[p], fmaf(b.y, cny[p], b.z * cnz[p]));
        const float lg = __log2f(fmaxf(d, 0.0f));  // -inf when d<=0 -> w=0
        const float tt = fabsf(a.w - czv[p]) * il2r[adx][p];
        // w = wn^128 * wxy * wd = exp2(128*lg + (kLG[adx]+kLG[ady]) - tt)
        const float e = fmaf(128.0f, lg, sA[adx] - tt);
        const float w = __builtin_amdgcn_exp2f(e);
        accx[p] = fmaf(a.x, w, accx[p]);
        accy[p] = fmaf(a.y, w, accy[p]);
        accz[p] = fmaf(a.z, w, accz[p]);
        accw[p] += w;
      }
    }
  }

#pragma unroll
  for (int p = 0; p < PX; ++p) {
    const int ox = bx * BX + tx * PX + p;
    const int oy = by * BY + ty;
    const int pix = plane + oy * W + ox;
    const float inv = 1.0f / accw[p];  // center tap weight==1 => accw>=1
    float* op = out + pix * 3;
    op[0] = accx[p] * inv;
    op[1] = accy[p] * inv;
    op[2] = accz[p] * inv;
  }
}

extern "C" void kernel_launch(void* const* d_in, const int* in_sizes, int n_in,
                              void* d_out, int out_size, void* d_ws, size_t ws_size,
                              hipStream_t stream) {
  const float* col = (const float*)d_in[0];
  const float* nrm = (const float*)d_in[1];
  const float* zdz = (const float*)d_in[2];
  float* out = (float*)d_out;
  const int H = 1024, W = 1024;
  const int B = in_sizes[0] / (3 * H * W);
  dim3 grid(W / BX, H / BY, B);
  bilateral_kernel<<<grid, dim3(256), 0, stream>>>(col, nrm, zdz, out, H, W);
}